// Round 2
// baseline (280.854 us; speedup 1.0000x reference)
//
#include <hip/hip_runtime.h>

// DeepSeek-MLA sparse attention, absorbed formulation, all fp32.
// B=2 NQ=1024 NKV=2048 K=64 D=1024 H=16 LAT=128 HD=64
//
// Absorption: scores[b,q,k,h] = <q_lat[h,:], c_sel[k,:]> with
//   q_lat[h,:] = sum_hd q[h,hd] * W_kv_up[h*64+hd, :]      (K-half rows)
// and out_head[h,:] = W_kv_up_V[h] @ (sum_k attn[k,h] * c_sel[k,:])
// -> never materializes k/v (68.7 GF -> ~12.9 GF total).
#define NQc   1024
#define NKVc  2048
#define KSEL  64
#define DIMc  1024
#define NH    16
#define LATc  128
#define BQ    2048   // B*NQ
#define SCALE 0.125f

// ---------------------------------------------------------------------------
// Generic fp32 GEMM-NT: C[m,n] = sum_k A[m*lda+k] * B[n*ldb+k]
// BM=64, BN template (64/128), BK=32, 256 threads, micro 4 x TN (TN=BN/16).
// blockIdx.z batches (per-head or split-K) via sAz/sBz/sCz element offsets.
// ---------------------------------------------------------------------------
template<int BN, int TN>
__global__ __launch_bounds__(256)
void gemm_nt(const float* __restrict__ A, int lda, long sAz,
             const float* __restrict__ Bm, int ldb, long sBz,
             float* __restrict__ C, int ldc, long sCz,
             int M, int N, int K) {
  A  += (size_t)blockIdx.z * sAz;
  Bm += (size_t)blockIdx.z * sBz;
  C  += (size_t)blockIdx.z * sCz;
  __shared__ float As[32][68];        // transposed [k][m], +4 pad
  __shared__ float Bs[32][BN + 4];    // transposed [k][n], +4 pad
  const int tid = threadIdx.x;
  const int bm = blockIdx.y * 64;
  const int bn = blockIdx.x * BN;
  const int tx = tid & 15;
  const int ty = tid >> 4;
  float acc[4][TN];
#pragma unroll
  for (int i = 0; i < 4; ++i)
#pragma unroll
    for (int j = 0; j < TN; ++j) acc[i][j] = 0.f;

  for (int k0 = 0; k0 < K; k0 += 32) {
    // stage A tile (64 x 32), transpose into As[k][m]
#pragma unroll
    for (int t = 0; t < 2; ++t) {
      int e = tid * 4 + t * 1024;
      int m = e >> 5, k = e & 31;
      float4 v = *(const float4*)(A + (size_t)(bm + m) * lda + (k0 + k));
      As[k + 0][m] = v.x; As[k + 1][m] = v.y; As[k + 2][m] = v.z; As[k + 3][m] = v.w;
    }
    // stage B tile (BN x 32), transpose into Bs[k][n]
#pragma unroll
    for (int t = 0; t < BN / 32; ++t) {
      int e = tid * 4 + t * 1024;
      int m = e >> 5, k = e & 31;
      float4 v = *(const float4*)(Bm + (size_t)(bn + m) * ldb + (k0 + k));
      Bs[k + 0][m] = v.x; Bs[k + 1][m] = v.y; Bs[k + 2][m] = v.z; Bs[k + 3][m] = v.w;
    }
    __syncthreads();
#pragma unroll
    for (int kk = 0; kk < 32; ++kk) {
      float4 a = *(const float4*)&As[kk][ty * 4];
      float al[4] = {a.x, a.y, a.z, a.w};
      float bl[TN];
#pragma unroll
      for (int j = 0; j < TN; j += 4) {
        float4 b = *(const float4*)&Bs[kk][tx * TN + j];
        bl[j] = b.x; bl[j + 1] = b.y; bl[j + 2] = b.z; bl[j + 3] = b.w;
      }
#pragma unroll
      for (int i = 0; i < 4; ++i)
#pragma unroll
        for (int j = 0; j < TN; ++j)
          acc[i][j] = fmaf(al[i], bl[j], acc[i][j]);
    }
    __syncthreads();
  }
#pragma unroll
  for (int i = 0; i < 4; ++i)
#pragma unroll
    for (int j = 0; j < TN; j += 4) {
      float4 v = make_float4(acc[i][j], acc[i][j + 1], acc[i][j + 2], acc[i][j + 3]);
      *(float4*)(C + (size_t)(bm + ty * 4 + i) * ldc + bn + tx * TN + j) = v;
    }
}

// ---------------------------------------------------------------------------
// q_lat per-head GEMM-NN: C[m,n] = sum_{k<64} A[m*lda+k] * B[k*ldb+n]
// N=128 fixed, K=64 fixed, BM=64. z = head.
// ---------------------------------------------------------------------------
__global__ __launch_bounds__(256)
void gemm_nn_k64(const float* __restrict__ A, int lda, long sAz,
                 const float* __restrict__ Bm, int ldb, long sBz,
                 float* __restrict__ C, int ldc, long sCz, int M) {
  A  += (size_t)blockIdx.z * sAz;
  Bm += (size_t)blockIdx.z * sBz;
  C  += (size_t)blockIdx.z * sCz;
  __shared__ float As[64][68];    // transposed [k][m]
  __shared__ float Bs[64][132];   // [k][n]
  const int tid = threadIdx.x;
  const int bm = blockIdx.y * 64;
  // A tile 64 x 64
#pragma unroll
  for (int t = 0; t < 4; ++t) {
    int e = tid * 4 + t * 1024;
    int m = e >> 6, k = e & 63;
    float4 v = *(const float4*)(A + (size_t)(bm + m) * lda + k);
    As[k + 0][m] = v.x; As[k + 1][m] = v.y; As[k + 2][m] = v.z; As[k + 3][m] = v.w;
  }
  // B tile 64 x 128 (row-contiguous in n, no transpose)
#pragma unroll
  for (int t = 0; t < 8; ++t) {
    int e = tid * 4 + t * 1024;
    int k = e >> 7, n = e & 127;
    *(float4*)&Bs[k][n] = *(const float4*)(Bm + (size_t)k * ldb + n);
  }
  __syncthreads();
  const int tx = tid & 15;   // n block: tx*8
  const int ty = tid >> 4;   // m block: ty*4
  float acc[4][8];
#pragma unroll
  for (int i = 0; i < 4; ++i)
#pragma unroll
    for (int j = 0; j < 8; ++j) acc[i][j] = 0.f;
#pragma unroll
  for (int kk = 0; kk < 64; ++kk) {
    float4 a  = *(const float4*)&As[kk][ty * 4];
    float4 b0 = *(const float4*)&Bs[kk][tx * 8];
    float4 b1 = *(const float4*)&Bs[kk][tx * 8 + 4];
    float al[4] = {a.x, a.y, a.z, a.w};
    float bl[8] = {b0.x, b0.y, b0.z, b0.w, b1.x, b1.y, b1.z, b1.w};
#pragma unroll
    for (int i = 0; i < 4; ++i)
#pragma unroll
      for (int j = 0; j < 8; ++j)
        acc[i][j] = fmaf(al[i], bl[j], acc[i][j]);
  }
#pragma unroll
  for (int i = 0; i < 4; ++i)
#pragma unroll
    for (int j = 0; j < 8; j += 4) {
      float4 v = make_float4(acc[i][j], acc[i][j + 1], acc[i][j + 2], acc[i][j + 3]);
      *(float4*)(C + (size_t)(bm + ty * 4 + i) * ldc + tx * 8 + j) = v;
    }
}

// ---------------------------------------------------------------------------
// split-K reduce: dst[i] = sum_{p<4} src[p*n + i]   (float4 granularity)
// ---------------------------------------------------------------------------
__global__ __launch_bounds__(256)
void reduce4(float* __restrict__ dst, const float* __restrict__ src, int n4) {
  int i = blockIdx.x * 256 + threadIdx.x;
  if (i >= n4) return;
  const float4* s = (const float4*)src;
  float4 a = s[i], b = s[i + n4], c = s[i + 2 * n4], d = s[i + 3 * n4];
  ((float4*)dst)[i] = make_float4(a.x + b.x + c.x + d.x, a.y + b.y + c.y + d.y,
                                  a.z + b.z + c.z + d.z, a.w + b.w + c.w + d.w);
}

// ---------------------------------------------------------------------------
// Fused sparse attention in latent space. One block per (b, q).
// scores[k,h] = SCALE * <q_lat[h,:], c_sel[k,:]>   (LAT=128 dots)
// attn = softmax_k(scores);  cw[h,:] = sum_k attn[k,h] * c_sel[k,:]
// ---------------------------------------------------------------------------
__global__ __launch_bounds__(256)
void attn_kernel(const float* __restrict__ c_kv,    // (B, NKV, LAT)
                 const float* __restrict__ q_lat,   // (B*NQ, H, LAT)
                 const int* __restrict__ indices,   // (B*NQ, K)
                 float* __restrict__ cw) {          // (B*NQ, H, LAT)
  const int bq = blockIdx.x;
  const int b = bq >> 10;            // NQ = 1024
  const int tid = threadIdx.x;
  __shared__ float qls[NH][LATc + 4];
  __shared__ float cs[KSEL][LATc + 4];
  __shared__ float sc[KSEL][NH + 4];
  // load q_lat for this query: 16x128
#pragma unroll
  for (int t = 0; t < 2; ++t) {
    int e = tid * 4 + t * 1024;
    int h = e >> 7, l = e & 127;
    *(float4*)&qls[h][l] = *(const float4*)(q_lat + (size_t)bq * (NH * LATc) + e);
  }
  // gather 64 selected latent rows (each 512B, 32 lanes x float4 per row)
#pragma unroll
  for (int t = 0; t < 8; ++t) {
    int r = t * 8 + (tid >> 5);
    int l = (tid & 31) * 4;
    int idx = indices[bq * KSEL + r];
    *(float4*)&cs[r][l] = *(const float4*)(c_kv + ((size_t)b * NKVc + idx) * LATc + l);
  }
  __syncthreads();
  // scores: thread -> row kr = tid/4, heads h0..h0+3 with h0 = (tid%4)*4
  {
    const int kr = tid >> 2;
    const int h0 = (tid & 3) * 4;
    float s0 = 0.f, s1 = 0.f, s2 = 0.f, s3 = 0.f;
#pragma unroll
    for (int l = 0; l < LATc; l += 4) {
      float4 c4 = *(const float4*)&cs[kr][l];
      float4 q0 = *(const float4*)&qls[h0 + 0][l];
      float4 q1 = *(const float4*)&qls[h0 + 1][l];
      float4 q2 = *(const float4*)&qls[h0 + 2][l];
      float4 q3 = *(const float4*)&qls[h0 + 3][l];
      s0 += c4.x * q0.x + c4.y * q0.y + c4.z * q0.z + c4.w * q0.w;
      s1 += c4.x * q1.x + c4.y * q1.y + c4.z * q1.z + c4.w * q1.w;
      s2 += c4.x * q2.x + c4.y * q2.y + c4.z * q2.z + c4.w * q2.w;
      s3 += c4.x * q3.x + c4.y * q3.y + c4.z * q3.z + c4.w * q3.w;
    }
    sc[kr][h0 + 0] = s0 * SCALE;
    sc[kr][h0 + 1] = s1 * SCALE;
    sc[kr][h0 + 2] = s2 * SCALE;
    sc[kr][h0 + 3] = s3 * SCALE;
  }
  __syncthreads();
  const int h = tid >> 4;            // head for softmax + PV
  // softmax over k (64 values) per head: 16 lanes per head, 4 values each
  {
    const int i = tid & 15;
    float v0 = sc[i * 4 + 0][h], v1 = sc[i * 4 + 1][h];
    float v2 = sc[i * 4 + 2][h], v3 = sc[i * 4 + 3][h];
    float mx = fmaxf(fmaxf(v0, v1), fmaxf(v2, v3));
#pragma unroll
    for (int m = 8; m; m >>= 1) mx = fmaxf(mx, __shfl_xor(mx, m));
    v0 = expf(v0 - mx); v1 = expf(v1 - mx); v2 = expf(v2 - mx); v3 = expf(v3 - mx);
    float sum = v0 + v1 + v2 + v3;
#pragma unroll
    for (int m = 8; m; m >>= 1) sum += __shfl_xor(sum, m);
    float inv = 1.f / sum;
    sc[i * 4 + 0][h] = v0 * inv; sc[i * 4 + 1][h] = v1 * inv;
    sc[i * 4 + 2][h] = v2 * inv; sc[i * 4 + 3][h] = v3 * inv;
  }
  __syncthreads();
  // PV: cw[h, l0..l0+7] = sum_k attn[k,h] * cs[k, l0..l0+7]
  {
    const int l0 = (tid & 15) * 8;
    float o[8] = {0.f, 0.f, 0.f, 0.f, 0.f, 0.f, 0.f, 0.f};
#pragma unroll
    for (int k = 0; k < KSEL; ++k) {
      float w = sc[k][h];
      float4 c0 = *(const float4*)&cs[k][l0];
      float4 c1 = *(const float4*)&cs[k][l0 + 4];
      o[0] = fmaf(w, c0.x, o[0]); o[1] = fmaf(w, c0.y, o[1]);
      o[2] = fmaf(w, c0.z, o[2]); o[3] = fmaf(w, c0.w, o[3]);
      o[4] = fmaf(w, c1.x, o[4]); o[5] = fmaf(w, c1.y, o[5]);
      o[6] = fmaf(w, c1.z, o[6]); o[7] = fmaf(w, c1.w, o[7]);
    }
    float* dst = cw + (size_t)bq * (NH * LATc) + h * LATc + l0;
    *(float4*)dst       = make_float4(o[0], o[1], o[2], o[3]);
    *(float4*)(dst + 4) = make_float4(o[4], o[5], o[6], o[7]);
  }
}

extern "C" void kernel_launch(void* const* d_in, const int* in_sizes, int n_in,
                              void* d_out, int out_size, void* d_ws, size_t ws_size,
                              hipStream_t stream) {
  const float* x_q    = (const float*)d_in[0];
  const float* x_kv   = (const float*)d_in[1];
  const int*   idx    = (const int*)  d_in[2];
  const float* W_q    = (const float*)d_in[3];
  const float* W_kvd  = (const float*)d_in[4];
  const float* W_kvu  = (const float*)d_in[5];
  const float* W_out  = (const float*)d_in[6];
  float* out = (float*)d_out;

  // Workspace layout (floats), with aliasing to cut footprint to 42 MB:
  //   q     [0,    2M)   -- dead after K3; 'o' reuses this region in K5/K6
  //   c_kv  [2M,   2.5M)
  //   q_lat [2.5M, 6.5M)
  //   cw    [6.5M, 10.5M) -- pbuf aliases this region (dead before K4 writes cw)
  float* ws    = (float*)d_ws;
  float* q     = ws;                       // 2048*1024
  float* c_kv  = q     + 2048 * 1024;      // 4096*128
  float* q_lat = c_kv  + 4096 * 128;       // 2048*2048
  float* cw    = q_lat + 2048 * 2048;      // 2048*2048
  float* pbuf  = cw;                       // 4*4096*128, alias (consumed pre-K4)
  float* o     = q;                        // 2048*1024, alias (q dead after K3)

  // K1: q = x_q @ W_q^T   (2048 x 1024, K=1024)
  gemm_nt<128, 8><<<dim3(8, 32, 1), 256, 0, stream>>>(
      x_q, 1024, 0, W_q, 1024, 0, q, 1024, 0, 2048, 1024, 1024);

  // K2: c_kv = x_kv @ W_kvd^T  (4096 x 128, K=1024), split-K x4 for occupancy
  gemm_nt<128, 8><<<dim3(1, 64, 4), 256, 0, stream>>>(
      x_kv, 1024, 256, W_kvd, 1024, 256, pbuf, 128, (long)4096 * 128,
      4096, 128, 256);
  reduce4<<<dim3(512), 256, 0, stream>>>(c_kv, pbuf, 4096 * 128 / 4);

  // K3: q_lat[bq,h,:] = q[bq,h*64:..] @ W_kvu[h*64:h*64+64, :]   (per head)
  gemm_nn_k64<<<dim3(1, 32, 16), 256, 0, stream>>>(
      q, 1024, 64, W_kvu, 128, (long)64 * 128, q_lat, 2048, 128, 2048);

  // K4: fused gather + latent scores + softmax + latent PV
  attn_kernel<<<dim3(2048), 256, 0, stream>>>(c_kv, q_lat, idx, cw);

  // K5: o[bq,h*64+d] = cw[bq,h,:] @ W_kvu[1024+h*64+d, :]^T  (per head, N=64,K=128)
  gemm_nt<64, 4><<<dim3(1, 32, 16), 256, 0, stream>>>(
      cw, 2048, 128, W_kvu + 1024 * 128, 128, (long)64 * 128,
      o, 1024, 64, 2048, 64, 128);

  // K6: out = o @ W_out^T  (2048 x 1024, K=1024)
  gemm_nt<128, 8><<<dim3(8, 32, 1), 256, 0, stream>>>(
      o, 1024, 0, W_out, 1024, 0, out, 1024, 0, 2048, 1024, 1024);
}

// Round 3
// 141.587 us; speedup vs baseline: 1.9836x; 1.9836x over previous
//
#include <hip/hip_runtime.h>

// DeepSeek-MLA sparse attention, absorbed formulation.
// B=2 NQ=1024 NKV=2048 K=64 D=1024 H=16 LAT=128 HD=64
// This round: K1/K6 (the two 2048x1024x1024 GEMMs, 80% of runtime) moved to
// bf16 MFMA (16x16x32, fp32 accum), 2-phase double-buffered global_load_lds
// staging with both-sides XOR swizzle. Everything else stays fp32.
#define NQc   1024
#define NKVc  2048
#define KSEL  64
#define DIMc  1024
#define NH    16
#define LATc  128
#define BQ    2048
#define SCALE 0.125f

typedef unsigned short u16;
typedef __attribute__((ext_vector_type(8))) short short8b;   // 8 bf16
typedef __attribute__((ext_vector_type(4))) float f32x4;

__device__ __forceinline__ u16 f2bf(float f) {
  unsigned int u = __float_as_uint(f);
  return (u16)((u + 0x7FFFu + ((u >> 16) & 1u)) >> 16);   // RNE
}

// ---------------------------------------------------------------------------
// fp32 -> bf16 elementwise, 8 elems/thread
// ---------------------------------------------------------------------------
__global__ __launch_bounds__(256)
void conv_f32_bf16(const float* __restrict__ in, u16* __restrict__ out, int n8) {
  int i = blockIdx.x * 256 + threadIdx.x;
  if (i >= n8) return;
  float4 f0 = ((const float4*)in)[i * 2];
  float4 f1 = ((const float4*)in)[i * 2 + 1];
  ushort4 a, b;
  a.x = f2bf(f0.x); a.y = f2bf(f0.y); a.z = f2bf(f0.z); a.w = f2bf(f0.w);
  b.x = f2bf(f1.x); b.y = f2bf(f1.y); b.z = f2bf(f1.z); b.w = f2bf(f1.w);
  ((ushort4*)out)[i * 2] = a;
  ((ushort4*)out)[i * 2 + 1] = b;
}

// ---------------------------------------------------------------------------
// bf16 MFMA GEMM-NT: C[m,n] = sum_k A[m,k]*B[n,k], A:MxK bf16, B:NxK bf16,
// C fp32. BM=128, BN=64, BK=32, 256 thr / 4 waves (2x2), wave tile 64x32.
// grid = (N/64, M/128). 2-phase double-buffered LDS via global_load_lds w=16.
// LDS layout: 16B slot s holds (row=s>>2, kchunk=(s&3)^((row>>1)&3)) -- the
// XOR spreads fragment ds_read_b128 across all 32 banks (conflict-free) while
// the staging source permutation stays within each 64B row (coalesced).
// ---------------------------------------------------------------------------
__global__ __launch_bounds__(256)
void gemm_bf16_nt(const u16* __restrict__ A, int lda,
                  const u16* __restrict__ B, int ldb,
                  float* __restrict__ C, int ldc, int K) {
  __shared__ __align__(16) u16 As[2][512 * 8];   // 2 x 8 KB
  __shared__ __align__(16) u16 Bs[2][256 * 8];   // 2 x 4 KB
  const int tid = threadIdx.x;
  const int w = tid >> 6, lane = tid & 63;
  const int bm = blockIdx.y * 128, bn = blockIdx.x * 64;
  const int wr = w >> 1, wc = w & 1;

  f32x4 acc[4][2] = {};

  auto stage = [&](int buf, int k0) {
    // A tile: 128 rows x 32 k (512 slots), 2 wave-instructions per wave
#pragma unroll
    for (int t = 0; t < 2; ++t) {
      int s = w * 128 + t * 64 + lane;
      int row = s >> 2;
      int kc = (s & 3) ^ ((row >> 1) & 3);
      const u16* g = A + (size_t)(bm + row) * lda + (k0 + kc * 8);
      __builtin_amdgcn_global_load_lds(
          (const __attribute__((address_space(1))) unsigned int*)g,
          (__attribute__((address_space(3))) unsigned int*)&As[buf][(w * 128 + t * 64) * 8],
          16, 0, 0);
    }
    // B tile: 64 rows x 32 k (256 slots), 1 per wave
    {
      int s = w * 64 + lane;
      int row = s >> 2;
      int kc = (s & 3) ^ ((row >> 1) & 3);
      const u16* g = B + (size_t)(bn + row) * ldb + (k0 + kc * 8);
      __builtin_amdgcn_global_load_lds(
          (const __attribute__((address_space(1))) unsigned int*)g,
          (__attribute__((address_space(3))) unsigned int*)&Bs[buf][(w * 64) * 8],
          16, 0, 0);
    }
  };

  auto compute = [&](int buf) {
    short8b a[4], b[2];
#pragma unroll
    for (int m = 0; m < 4; ++m) {
      int row = wr * 64 + m * 16 + (lane & 15);
      int slot = row * 4 + ((lane >> 4) ^ ((row >> 1) & 3));
      a[m] = *(const short8b*)&As[buf][slot * 8];
    }
#pragma unroll
    for (int n = 0; n < 2; ++n) {
      int col = wc * 32 + n * 16 + (lane & 15);
      int slot = col * 4 + ((lane >> 4) ^ ((col >> 1) & 3));
      b[n] = *(const short8b*)&Bs[buf][slot * 8];
    }
#pragma unroll
    for (int m = 0; m < 4; ++m)
#pragma unroll
      for (int n = 0; n < 2; ++n)
        acc[m][n] = __builtin_amdgcn_mfma_f32_16x16x32_bf16(a[m], b[n], acc[m][n], 0, 0, 0);
  };

  stage(0, 0);
  asm volatile("s_waitcnt vmcnt(0)" ::: "memory");
  __syncthreads();
  const int nk = K >> 5;
  for (int t = 0; t < nk; ++t) {
    int cur = t & 1;
    if (t + 1 < nk) stage(cur ^ 1, (t + 1) << 5);   // prefetch hides under MFMA
    compute(cur);
    asm volatile("s_waitcnt vmcnt(0)" ::: "memory");
    __syncthreads();
  }

  // C/D layout: col = lane&15, row = (lane>>4)*4 + reg   [m89-verified]
#pragma unroll
  for (int m = 0; m < 4; ++m) {
    int row0 = bm + wr * 64 + m * 16 + (lane >> 4) * 4;
#pragma unroll
    for (int n = 0; n < 2; ++n) {
      int col = bn + wc * 32 + n * 16 + (lane & 15);
#pragma unroll
      for (int r = 0; r < 4; ++r)
        C[(size_t)(row0 + r) * ldc + col] = acc[m][n][r];
    }
  }
}

// ---------------------------------------------------------------------------
// Generic fp32 GEMM-NT (kept for K2, K5): C[m,n] = sum_k A[m,k]*B[n,k]
// OBF=true (requires TN==4): write bf16 to Cb instead of fp32 to C.
// ---------------------------------------------------------------------------
template<int BN, int TN, bool OBF>
__global__ __launch_bounds__(256)
void gemm_nt(const float* __restrict__ A, int lda, long sAz,
             const float* __restrict__ Bm, int ldb, long sBz,
             float* __restrict__ C, u16* __restrict__ Cb, int ldc, long sCz,
             int M, int N, int K) {
  A  += (size_t)blockIdx.z * sAz;
  Bm += (size_t)blockIdx.z * sBz;
  __shared__ float Ass[32][68];
  __shared__ float Bss[32][BN + 4];
  const int tid = threadIdx.x;
  const int bm = blockIdx.y * 64;
  const int bn = blockIdx.x * BN;
  const int tx = tid & 15;
  const int ty = tid >> 4;
  float acc[4][TN];
#pragma unroll
  for (int i = 0; i < 4; ++i)
#pragma unroll
    for (int j = 0; j < TN; ++j) acc[i][j] = 0.f;

  for (int k0 = 0; k0 < K; k0 += 32) {
#pragma unroll
    for (int t = 0; t < 2; ++t) {
      int e = tid * 4 + t * 1024;
      int m = e >> 5, k = e & 31;
      float4 v = *(const float4*)(A + (size_t)(bm + m) * lda + (k0 + k));
      Ass[k + 0][m] = v.x; Ass[k + 1][m] = v.y; Ass[k + 2][m] = v.z; Ass[k + 3][m] = v.w;
    }
#pragma unroll
    for (int t = 0; t < BN / 32; ++t) {
      int e = tid * 4 + t * 1024;
      int m = e >> 5, k = e & 31;
      float4 v = *(const float4*)(Bm + (size_t)(bn + m) * ldb + (k0 + k));
      Bss[k + 0][m] = v.x; Bss[k + 1][m] = v.y; Bss[k + 2][m] = v.z; Bss[k + 3][m] = v.w;
    }
    __syncthreads();
#pragma unroll
    for (int kk = 0; kk < 32; ++kk) {
      float4 a = *(const float4*)&Ass[kk][ty * 4];
      float al[4] = {a.x, a.y, a.z, a.w};
      float bl[TN];
#pragma unroll
      for (int j = 0; j < TN; j += 4) {
        float4 b = *(const float4*)&Bss[kk][tx * TN + j];
        bl[j] = b.x; bl[j + 1] = b.y; bl[j + 2] = b.z; bl[j + 3] = b.w;
      }
#pragma unroll
      for (int i = 0; i < 4; ++i)
#pragma unroll
        for (int j = 0; j < TN; ++j)
          acc[i][j] = fmaf(al[i], bl[j], acc[i][j]);
    }
    __syncthreads();
  }
  if constexpr (OBF) {
    static_assert(!OBF || TN == 4, "bf16 out needs TN==4");
    u16* Cz = Cb + (size_t)blockIdx.z * sCz;
#pragma unroll
    for (int i = 0; i < 4; ++i) {
      ushort4 v;
      v.x = f2bf(acc[i][0]); v.y = f2bf(acc[i][1]);
      v.z = f2bf(acc[i][2]); v.w = f2bf(acc[i][3]);
      *(ushort4*)(Cz + (size_t)(bm + ty * 4 + i) * ldc + bn + tx * 4) = v;
    }
  } else {
    float* Cz = C + (size_t)blockIdx.z * sCz;
#pragma unroll
    for (int i = 0; i < 4; ++i)
#pragma unroll
      for (int j = 0; j < TN; j += 4) {
        float4 v = make_float4(acc[i][j], acc[i][j + 1], acc[i][j + 2], acc[i][j + 3]);
        *(float4*)(Cz + (size_t)(bm + ty * 4 + i) * ldc + bn + tx * TN + j) = v;
      }
  }
}

// ---------------------------------------------------------------------------
// q_lat per-head GEMM-NN: C[m,n] = sum_{k<64} A[m,k]*B[k,n], N=128, z=head
// ---------------------------------------------------------------------------
__global__ __launch_bounds__(256)
void gemm_nn_k64(const float* __restrict__ A, int lda, long sAz,
                 const float* __restrict__ Bm, int ldb, long sBz,
                 float* __restrict__ C, int ldc, long sCz, int M) {
  A  += (size_t)blockIdx.z * sAz;
  Bm += (size_t)blockIdx.z * sBz;
  C  += (size_t)blockIdx.z * sCz;
  __shared__ float Ass[64][68];
  __shared__ float Bss[64][132];
  const int tid = threadIdx.x;
  const int bm = blockIdx.y * 64;
#pragma unroll
  for (int t = 0; t < 4; ++t) {
    int e = tid * 4 + t * 1024;
    int m = e >> 6, k = e & 63;
    float4 v = *(const float4*)(A + (size_t)(bm + m) * lda + k);
    Ass[k + 0][m] = v.x; Ass[k + 1][m] = v.y; Ass[k + 2][m] = v.z; Ass[k + 3][m] = v.w;
  }
#pragma unroll
  for (int t = 0; t < 8; ++t) {
    int e = tid * 4 + t * 1024;
    int k = e >> 7, n = e & 127;
    *(float4*)&Bss[k][n] = *(const float4*)(Bm + (size_t)k * ldb + n);
  }
  __syncthreads();
  const int tx = tid & 15;
  const int ty = tid >> 4;
  float acc[4][8];
#pragma unroll
  for (int i = 0; i < 4; ++i)
#pragma unroll
    for (int j = 0; j < 8; ++j) acc[i][j] = 0.f;
#pragma unroll
  for (int kk = 0; kk < 64; ++kk) {
    float4 a  = *(const float4*)&Ass[kk][ty * 4];
    float4 b0 = *(const float4*)&Bss[kk][tx * 8];
    float4 b1 = *(const float4*)&Bss[kk][tx * 8 + 4];
    float al[4] = {a.x, a.y, a.z, a.w};
    float bl[8] = {b0.x, b0.y, b0.z, b0.w, b1.x, b1.y, b1.z, b1.w};
#pragma unroll
    for (int i = 0; i < 4; ++i)
#pragma unroll
      for (int j = 0; j < 8; ++j)
        acc[i][j] = fmaf(al[i], bl[j], acc[i][j]);
  }
#pragma unroll
  for (int i = 0; i < 4; ++i)
#pragma unroll
    for (int j = 0; j < 8; j += 4) {
      float4 v = make_float4(acc[i][j], acc[i][j + 1], acc[i][j + 2], acc[i][j + 3]);
      *(float4*)(C + (size_t)(bm + ty * 4 + i) * ldc + tx * 8 + j) = v;
    }
}

// ---------------------------------------------------------------------------
// split-K reduce: dst[i] = sum_{p<4} src[p*n + i]
// ---------------------------------------------------------------------------
__global__ __launch_bounds__(256)
void reduce4(float* __restrict__ dst, const float* __restrict__ src, int n4) {
  int i = blockIdx.x * 256 + threadIdx.x;
  if (i >= n4) return;
  const float4* s = (const float4*)src;
  float4 a = s[i], b = s[i + n4], c = s[i + 2 * n4], d = s[i + 3 * n4];
  ((float4*)dst)[i] = make_float4(a.x + b.x + c.x + d.x, a.y + b.y + c.y + d.y,
                                  a.z + b.z + c.z + d.z, a.w + b.w + c.w + d.w);
}

// ---------------------------------------------------------------------------
// Fused sparse attention in latent space. One block per (b, q).
// ---------------------------------------------------------------------------
__global__ __launch_bounds__(256)
void attn_kernel(const float* __restrict__ c_kv,
                 const float* __restrict__ q_lat,
                 const int* __restrict__ indices,
                 float* __restrict__ cw) {
  const int bq = blockIdx.x;
  const int b = bq >> 10;
  const int tid = threadIdx.x;
  __shared__ float qls[NH][LATc + 4];
  __shared__ float cs[KSEL][LATc + 4];
  __shared__ float sc[KSEL][NH + 4];
#pragma unroll
  for (int t = 0; t < 2; ++t) {
    int e = tid * 4 + t * 1024;
    int h = e >> 7, l = e & 127;
    *(float4*)&qls[h][l] = *(const float4*)(q_lat + (size_t)bq * (NH * LATc) + e);
  }
#pragma unroll
  for (int t = 0; t < 8; ++t) {
    int r = t * 8 + (tid >> 5);
    int l = (tid & 31) * 4;
    int idx = indices[bq * KSEL + r];
    *(float4*)&cs[r][l] = *(const float4*)(c_kv + ((size_t)b * NKVc + idx) * LATc + l);
  }
  __syncthreads();
  {
    const int kr = tid >> 2;
    const int h0 = (tid & 3) * 4;
    float s0 = 0.f, s1 = 0.f, s2 = 0.f, s3 = 0.f;
#pragma unroll
    for (int l = 0; l < LATc; l += 4) {
      float4 c4 = *(const float4*)&cs[kr][l];
      float4 q0 = *(const float4*)&qls[h0 + 0][l];
      float4 q1 = *(const float4*)&qls[h0 + 1][l];
      float4 q2 = *(const float4*)&qls[h0 + 2][l];
      float4 q3 = *(const float4*)&qls[h0 + 3][l];
      s0 += c4.x * q0.x + c4.y * q0.y + c4.z * q0.z + c4.w * q0.w;
      s1 += c4.x * q1.x + c4.y * q1.y + c4.z * q1.z + c4.w * q1.w;
      s2 += c4.x * q2.x + c4.y * q2.y + c4.z * q2.z + c4.w * q2.w;
      s3 += c4.x * q3.x + c4.y * q3.y + c4.z * q3.z + c4.w * q3.w;
    }
    sc[kr][h0 + 0] = s0 * SCALE;
    sc[kr][h0 + 1] = s1 * SCALE;
    sc[kr][h0 + 2] = s2 * SCALE;
    sc[kr][h0 + 3] = s3 * SCALE;
  }
  __syncthreads();
  const int h = tid >> 4;
  {
    const int i = tid & 15;
    float v0 = sc[i * 4 + 0][h], v1 = sc[i * 4 + 1][h];
    float v2 = sc[i * 4 + 2][h], v3 = sc[i * 4 + 3][h];
    float mx = fmaxf(fmaxf(v0, v1), fmaxf(v2, v3));
#pragma unroll
    for (int m = 8; m; m >>= 1) mx = fmaxf(mx, __shfl_xor(mx, m));
    v0 = expf(v0 - mx); v1 = expf(v1 - mx); v2 = expf(v2 - mx); v3 = expf(v3 - mx);
    float sum = v0 + v1 + v2 + v3;
#pragma unroll
    for (int m = 8; m; m >>= 1) sum += __shfl_xor(sum, m);
    float inv = 1.f / sum;
    sc[i * 4 + 0][h] = v0 * inv; sc[i * 4 + 1][h] = v1 * inv;
    sc[i * 4 + 2][h] = v2 * inv; sc[i * 4 + 3][h] = v3 * inv;
  }
  __syncthreads();
  {
    const int l0 = (tid & 15) * 8;
    float o[8] = {0.f, 0.f, 0.f, 0.f, 0.f, 0.f, 0.f, 0.f};
#pragma unroll
    for (int k = 0; k < KSEL; ++k) {
      float w = sc[k][h];
      float4 c0 = *(const float4*)&cs[k][l0];
      float4 c1 = *(const float4*)&cs[k][l0 + 4];
      o[0] = fmaf(w, c0.x, o[0]); o[1] = fmaf(w, c0.y, o[1]);
      o[2] = fmaf(w, c0.z, o[2]); o[3] = fmaf(w, c0.w, o[3]);
      o[4] = fmaf(w, c1.x, o[4]); o[5] = fmaf(w, c1.y, o[5]);
      o[6] = fmaf(w, c1.z, o[6]); o[7] = fmaf(w, c1.w, o[7]);
    }
    float* dst = cw + (size_t)bq * (NH * LATc) + h * LATc + l0;
    *(float4*)dst       = make_float4(o[0], o[1], o[2], o[3]);
    *(float4*)(dst + 4) = make_float4(o[4], o[5], o[6], o[7]);
  }
}

extern "C" void kernel_launch(void* const* d_in, const int* in_sizes, int n_in,
                              void* d_out, int out_size, void* d_ws, size_t ws_size,
                              hipStream_t stream) {
  const float* x_q    = (const float*)d_in[0];
  const float* x_kv   = (const float*)d_in[1];
  const int*   idx    = (const int*)  d_in[2];
  const float* W_q    = (const float*)d_in[3];
  const float* W_kvd  = (const float*)d_in[4];
  const float* W_kvu  = (const float*)d_in[5];
  const float* W_out  = (const float*)d_in[6];
  float* out = (float*)d_out;

  // Workspace (floats), 42 MB total (same footprint as the passing round):
  //   q     [0, 2M)       fp32; after K3 dead -> hosts o_bf + wout_bf
  //   c_kv  [2M, 2.5M)
  //   q_lat [2.5M, 6.5M)  written at K3; before that hosts xq_bf + wq_bf
  //   cw    [6.5M, 10.5M) written at K4; before that hosts pbuf (K2 partials)
  float* ws    = (float*)d_ws;
  float* q     = ws;
  float* c_kv  = ws + 2 * 1024 * 1024;
  float* q_lat = c_kv + 512 * 1024;
  float* cw    = q_lat + 4 * 1024 * 1024;
  float* pbuf  = cw;                                   // alias (dead pre-K4)
  u16* xq_bf   = (u16*)q_lat;                          // 2M u16, dead pre-K3
  u16* wq_bf   = (u16*)(q_lat + 1024 * 1024);          // 1M u16, dead pre-K3
  u16* o_bf    = (u16*)q;                              // 2M u16, written post-K3
  u16* wout_bf = (u16*)(q + 1024 * 1024);              // 1M u16, written post-K3

  // convert K1 operands to bf16
  conv_f32_bf16<<<dim3(1024), 256, 0, stream>>>(x_q, xq_bf, 2048 * 1024 / 8);
  conv_f32_bf16<<<dim3(512), 256, 0, stream>>>(W_q, wq_bf, 1024 * 1024 / 8);

  // K2: c_kv = x_kv @ W_kvd^T  (4096 x 128, K=1024), split-K x4
  gemm_nt<128, 8, false><<<dim3(1, 64, 4), 256, 0, stream>>>(
      x_kv, 1024, 256, W_kvd, 1024, 256, pbuf, nullptr, 128, (long)4096 * 128,
      4096, 128, 256);
  reduce4<<<dim3(512), 256, 0, stream>>>(c_kv, pbuf, 4096 * 128 / 4);

  // K1: q = x_q @ W_q^T  (bf16 MFMA, fp32 out)
  gemm_bf16_nt<<<dim3(16, 16), 256, 0, stream>>>(xq_bf, 1024, wq_bf, 1024,
                                                 q, 1024, 1024);

  // K3: q_lat = per-head q @ W_kvu_K  (fp32)
  gemm_nn_k64<<<dim3(1, 32, 16), 256, 0, stream>>>(
      q, 1024, 64, W_kvu, 128, (long)64 * 128, q_lat, 2048, 128, 2048);

  // convert W_out (q region is dead after K3; stream order guarantees safety)
  conv_f32_bf16<<<dim3(512), 256, 0, stream>>>(W_out, wout_bf, 1024 * 1024 / 8);

  // K4: fused gather + latent scores + softmax + latent PV
  attn_kernel<<<dim3(2048), 256, 0, stream>>>(c_kv, q_lat, idx, cw);

  // K5: o_bf = per-head cw @ W_kvu_V^T (fp32 compute, bf16 store)
  gemm_nt<64, 4, true><<<dim3(1, 32, 16), 256, 0, stream>>>(
      cw, 2048, 128, W_kvu + 1024 * 128, 128, (long)64 * 128,
      nullptr, o_bf, 1024, 64, 2048, 64, 128);

  // K6: out = o @ W_out^T  (bf16 MFMA, fp32 out)
  gemm_bf16_nt<<<dim3(16, 16), 256, 0, stream>>>(o_bf, 1024, wout_bf, 1024,
                                                 out, 1024, 1024);
}

// Round 5
// 93.945 us; speedup vs baseline: 2.9895x; 1.5071x over previous
//
#include <hip/hip_runtime.h>

// DeepSeek-MLA sparse attention, absorbed formulation, full bf16-MFMA pipeline.
// B=2 NQ=1024 NKV=2048 K=64 D=1024 H=16 LAT=128 HD=64
// Round-5 fix: x_kv has B*NKV*D = 4,194,304 elements (round 4 converted only
// half -> batch-1 c_kv was poison garbage, absmax 1.25). xkv_bf is 8 MB.
#define NKVc  2048
#define SCALE 0.125f

typedef unsigned short u16;
typedef __attribute__((ext_vector_type(8))) short short8b;     // 8 bf16 (MFMA frag)
typedef __attribute__((ext_vector_type(8))) unsigned short ushort8;
typedef __attribute__((ext_vector_type(4))) float f32x4;

__device__ __forceinline__ u16 f2bf(float f) {
  unsigned int u = __float_as_uint(f);
  return (u16)((u + 0x7FFFu + ((u >> 16) & 1u)) >> 16);   // RNE
}

// ---------------------------------------------------------------------------
// fp32 -> bf16 elementwise, 8 elems/thread
// ---------------------------------------------------------------------------
__global__ __launch_bounds__(256)
void conv_f32_bf16(const float* __restrict__ in, u16* __restrict__ out, int n8) {
  int i = blockIdx.x * 256 + threadIdx.x;
  if (i >= n8) return;
  float4 f0 = ((const float4*)in)[i * 2];
  float4 f1 = ((const float4*)in)[i * 2 + 1];
  ushort4 a, b;
  a.x = f2bf(f0.x); a.y = f2bf(f0.y); a.z = f2bf(f0.z); a.w = f2bf(f0.w);
  b.x = f2bf(f1.x); b.y = f2bf(f1.y); b.z = f2bf(f1.z); b.w = f2bf(f1.w);
  ((ushort4*)out)[i * 2] = a;
  ((ushort4*)out)[i * 2 + 1] = b;
}

// wkt[h][l][hd] = W_kvu[h*64+hd][l]  (K-half, transposed per head), bf16
__global__ __launch_bounds__(256)
void conv_wkt(const float* __restrict__ Wk, u16* __restrict__ wkt) {
  int o = blockIdx.x * 256 + threadIdx.x;   // ((h*128)+l)*64 + hd
  int hd = o & 63;
  int l = (o >> 6) & 127;
  int h = o >> 13;
  wkt[o] = f2bf(Wk[(h * 64 + hd) * 128 + l]);
}

// split-K reduce, bf16 out: dst[i] = bf16(sum_{p<4} src[p*n + i])
__global__ __launch_bounds__(256)
void reduce4b(u16* __restrict__ dst, const float* __restrict__ src, int n4) {
  int i = blockIdx.x * 256 + threadIdx.x;
  if (i >= n4) return;
  const float4* s = (const float4*)src;
  float4 a = s[i], b = s[i + n4], c = s[i + 2 * n4], d = s[i + 3 * n4];
  ushort4 v;
  v.x = f2bf(a.x + b.x + c.x + d.x); v.y = f2bf(a.y + b.y + c.y + d.y);
  v.z = f2bf(a.z + b.z + c.z + d.z); v.w = f2bf(a.w + b.w + c.w + d.w);
  ((ushort4*)dst)[i] = v;
}

// ---------------------------------------------------------------------------
// bf16 MFMA GEMM-NT, z-batched: C[m,n] = sum_k A[m,k]*B[n,k]
// BM=128, BN=64, BK=32, 256 thr / 4 waves (2x2). OBF: write bf16 to Cb.
// Both-sides XOR swizzle, global_load_lds w=16, 2-phase double buffer
// (structure validated in round 3).
// ---------------------------------------------------------------------------
template<bool OBF>
__global__ __launch_bounds__(256)
void gemm_bf16_nt(const u16* __restrict__ A, int lda, long sAz,
                  const u16* __restrict__ B, int ldb, long sBz,
                  float* __restrict__ C, u16* __restrict__ Cb,
                  int ldc, long sCz, int K) {
  A += (size_t)blockIdx.z * sAz;
  B += (size_t)blockIdx.z * sBz;
  __shared__ __align__(16) u16 As[2][512 * 8];   // 2 x 8 KB
  __shared__ __align__(16) u16 Bs[2][256 * 8];   // 2 x 4 KB
  const int tid = threadIdx.x;
  const int w = tid >> 6, lane = tid & 63;
  const int bm = blockIdx.y * 128, bn = blockIdx.x * 64;
  const int wr = w >> 1, wc = w & 1;

  f32x4 acc[4][2] = {};

  auto stage = [&](int buf, int k0) {
#pragma unroll
    for (int t = 0; t < 2; ++t) {
      int s = w * 128 + t * 64 + lane;
      int row = s >> 2;
      int kc = (s & 3) ^ ((row >> 1) & 3);
      const u16* g = A + (size_t)(bm + row) * lda + (k0 + kc * 8);
      __builtin_amdgcn_global_load_lds(
          (const __attribute__((address_space(1))) unsigned int*)g,
          (__attribute__((address_space(3))) unsigned int*)&As[buf][(w * 128 + t * 64) * 8],
          16, 0, 0);
    }
    {
      int s = w * 64 + lane;
      int row = s >> 2;
      int kc = (s & 3) ^ ((row >> 1) & 3);
      const u16* g = B + (size_t)(bn + row) * ldb + (k0 + kc * 8);
      __builtin_amdgcn_global_load_lds(
          (const __attribute__((address_space(1))) unsigned int*)g,
          (__attribute__((address_space(3))) unsigned int*)&Bs[buf][(w * 64) * 8],
          16, 0, 0);
    }
  };

  auto compute = [&](int buf) {
    short8b a[4], b[2];
#pragma unroll
    for (int m = 0; m < 4; ++m) {
      int row = wr * 64 + m * 16 + (lane & 15);
      int slot = row * 4 + ((lane >> 4) ^ ((row >> 1) & 3));
      a[m] = *(const short8b*)&As[buf][slot * 8];
    }
#pragma unroll
    for (int n = 0; n < 2; ++n) {
      int col = wc * 32 + n * 16 + (lane & 15);
      int slot = col * 4 + ((lane >> 4) ^ ((col >> 1) & 3));
      b[n] = *(const short8b*)&Bs[buf][slot * 8];
    }
#pragma unroll
    for (int m = 0; m < 4; ++m)
#pragma unroll
      for (int n = 0; n < 2; ++n)
        acc[m][n] = __builtin_amdgcn_mfma_f32_16x16x32_bf16(a[m], b[n], acc[m][n], 0, 0, 0);
  };

  stage(0, 0);
  asm volatile("s_waitcnt vmcnt(0)" ::: "memory");
  __syncthreads();
  const int nk = K >> 5;
  for (int t = 0; t < nk; ++t) {
    int cur = t & 1;
    if (t + 1 < nk) stage(cur ^ 1, (t + 1) << 5);
    compute(cur);
    asm volatile("s_waitcnt vmcnt(0)" ::: "memory");
    __syncthreads();
  }

#pragma unroll
  for (int m = 0; m < 4; ++m) {
    int row0 = bm + wr * 64 + m * 16 + (lane >> 4) * 4;
#pragma unroll
    for (int n = 0; n < 2; ++n) {
      int col = bn + wc * 32 + n * 16 + (lane & 15);
      if constexpr (OBF) {
        u16* Cz = Cb + (size_t)blockIdx.z * sCz;
#pragma unroll
        for (int r = 0; r < 4; ++r)
          Cz[(size_t)(row0 + r) * ldc + col] = f2bf(acc[m][n][r]);
      } else {
        float* Cz = C + (size_t)blockIdx.z * sCz;
#pragma unroll
        for (int r = 0; r < 4; ++r)
          Cz[(size_t)(row0 + r) * ldc + col] = acc[m][n][r];
      }
    }
  }
}

// ---------------------------------------------------------------------------
// Fused sparse attention in latent space, bf16 MFMA. One block per (b,q).
// scores = cs(64x128) x qls^T(16x128) -> softmax_k -> cw = P^T(16x64) x cs.
// ---------------------------------------------------------------------------
__global__ __launch_bounds__(256)
void attn_mfma(const u16* __restrict__ c_kvb,   // (B, 2048, 128) bf16
               const u16* __restrict__ q_latb,  // (BQ, 16, 128) bf16
               const int* __restrict__ indices, // (BQ, 64)
               u16* __restrict__ cw_bf) {       // (BQ, 16, 128) bf16
  __shared__ __align__(16) u16 qls[256 * 8];    // 4 KB swizzled 16x128
  __shared__ __align__(16) u16 csa[1024 * 8];   // 16 KB swizzled 64x128
  __shared__ __align__(16) u16 cst[128 * 72];   // 18 KB [lat][k]+pad
  __shared__ __align__(16) u16 pT[16 * 72];     // P^T [h][k]+pad
  __shared__ __align__(16) float redmax[64];
  __shared__ __align__(16) float redsum[64];
  __shared__ __align__(16) u16 outst[2048];     // 4 KB out staging

  const int tid = threadIdx.x;
  const int w = tid >> 6, lane = tid & 63;
  const int bq = blockIdx.x;
  const int b = bq >> 10;

  // load q_lat 16x128 bf16, chunk-XOR swizzle: slot = h*16 + (c^h)
  {
    int h = tid >> 4, c = tid & 15;
    ushort8 v = *(const ushort8*)(q_latb + (size_t)bq * 2048 + tid * 8);
    *(ushort8*)&qls[(h * 16 + (c ^ h)) * 8] = v;
  }
  // gather: wave w owns lat quarter [w*32, w*32+32), lane owns k-row `lane`
  {
    int kidx = indices[bq * 64 + lane];
    const u16* src = c_kvb + ((size_t)b * NKVc + kidx) * 128 + w * 32;
    ushort8 v[4];
#pragma unroll
    for (int t = 0; t < 4; ++t) v[t] = *(const ushort8*)(src + t * 8);
#pragma unroll
    for (int t = 0; t < 4; ++t) {
      int c = w * 4 + t;
      *(ushort8*)&csa[(lane * 16 + (c ^ (lane & 15))) * 8] = v[t];
    }
#pragma unroll
    for (int t = 0; t < 4; ++t)
#pragma unroll
      for (int j = 0; j < 8; ++j)
        cst[(w * 32 + t * 8 + j) * 72 + lane] = v[t][j];
  }
  __syncthreads();

  // scores: wave w -> S[k = w*16 + (lane>>4)*4 + r][h = lane&15]
  f32x4 sacc = {};
#pragma unroll
  for (int kc = 0; kc < 4; ++kc) {
    int ar = w * 16 + (lane & 15);
    int ac = kc * 4 + (lane >> 4);
    short8b av = *(const short8b*)&csa[(ar * 16 + (ac ^ (ar & 15))) * 8];
    int bh = lane & 15;
    short8b bv = *(const short8b*)&qls[(bh * 16 + (ac ^ bh)) * 8];
    sacc = __builtin_amdgcn_mfma_f32_16x16x32_bf16(av, bv, sacc, 0, 0, 0);
  }
  float s0 = sacc[0] * SCALE, s1 = sacc[1] * SCALE;
  float s2 = sacc[2] * SCALE, s3 = sacc[3] * SCALE;
  float mx = fmaxf(fmaxf(s0, s1), fmaxf(s2, s3));
  mx = fmaxf(mx, __shfl_xor(mx, 16));
  mx = fmaxf(mx, __shfl_xor(mx, 32));
  if (lane < 16) redmax[w * 16 + lane] = mx;
  __syncthreads();
  const int h = lane & 15;
  float m4 = fmaxf(fmaxf(redmax[h], redmax[16 + h]),
                   fmaxf(redmax[32 + h], redmax[48 + h]));
  float p0 = __expf(s0 - m4), p1 = __expf(s1 - m4);
  float p2 = __expf(s2 - m4), p3 = __expf(s3 - m4);
  float sm = p0 + p1 + p2 + p3;
  sm += __shfl_xor(sm, 16);
  sm += __shfl_xor(sm, 32);
  if (lane < 16) redsum[w * 16 + lane] = sm;
  __syncthreads();
  float tot = redsum[h] + redsum[16 + h] + redsum[32 + h] + redsum[48 + h];
  float inv = 1.0f / tot;
  {
    ushort4 pw;
    pw.x = f2bf(p0 * inv); pw.y = f2bf(p1 * inv);
    pw.z = f2bf(p2 * inv); pw.w = f2bf(p3 * inv);
    *(ushort4*)&pT[h * 72 + w * 16 + (lane >> 4) * 4] = pw;
  }
  __syncthreads();

  // PV: wave w computes C[h 0..15][n = w*32 .. w*32+32]
  f32x4 pacc0 = {}, pacc1 = {};
#pragma unroll
  for (int kc = 0; kc < 2; ++kc) {
    short8b pa = *(const short8b*)&pT[(lane & 15) * 72 + kc * 32 + (lane >> 4) * 8];
    int cch = kc * 4 + (lane >> 4);
    int n0 = w * 32 + (lane & 15);
    short8b b0 = *(const short8b*)&cst[n0 * 72 + cch * 8];
    short8b b1 = *(const short8b*)&cst[(n0 + 16) * 72 + cch * 8];
    pacc0 = __builtin_amdgcn_mfma_f32_16x16x32_bf16(pa, b0, pacc0, 0, 0, 0);
    pacc1 = __builtin_amdgcn_mfma_f32_16x16x32_bf16(pa, b1, pacc1, 0, 0, 0);
  }
#pragma unroll
  for (int r = 0; r < 4; ++r) {
    int hh = (lane >> 4) * 4 + r;
    outst[hh * 128 + w * 32 + (lane & 15)] = f2bf(pacc0[r]);
    outst[hh * 128 + w * 32 + 16 + (lane & 15)] = f2bf(pacc1[r]);
  }
  __syncthreads();
  *(ushort8*)(cw_bf + (size_t)bq * 2048 + tid * 8) = *(const ushort8*)&outst[tid * 8];
}

extern "C" void kernel_launch(void* const* d_in, const int* in_sizes, int n_in,
                              void* d_out, int out_size, void* d_ws, size_t ws_size,
                              hipStream_t stream) {
  const float* x_q    = (const float*)d_in[0];
  const float* x_kv   = (const float*)d_in[1];
  const int*   idx    = (const int*)  d_in[2];
  const float* W_q    = (const float*)d_in[3];
  const float* W_kvd  = (const float*)d_in[4];
  const float* W_kvu  = (const float*)d_in[5];
  const float* W_out  = (const float*)d_in[6];
  float* out = (float*)d_out;

  // byte-offset workspace carve; top = 42 MB (round-2-proven footprint)
  char* wsb = (char*)d_ws;
  u16* xq_bf   = (u16*)(wsb + 0);                            // 4 MB
  u16* wq_bf   = (u16*)(wsb + (4u << 20));                   // 2 MB
  u16* xkv_bf  = (u16*)(wsb + (6u << 20));                   // 8 MB (B*NKV*D)
  u16* wkvd_bf = (u16*)(wsb + (14u << 20));                  // 256 KB
  u16* wkt     = (u16*)(wsb + (14u << 20) + (256u << 10));   // 256 KB
  u16* wv_bf   = (u16*)(wsb + (14u << 20) + (512u << 10));   // 256 KB
  u16* wout_bf = (u16*)(wsb + (14u << 20) + (768u << 10));   // 2 MB
  u16* q_bf    = (u16*)(wsb + (17u << 20));                  // 4 MB
  u16* c_kvb   = (u16*)(wsb + (21u << 20));                  // 1 MB
  u16* qlat_bf = (u16*)(wsb + (22u << 20));                  // 8 MB
  u16* cw_bf   = (u16*)(wsb + (30u << 20));                  // 8 MB
  u16* o_bf    = (u16*)(wsb + (38u << 20));                  // 4 MB
  float* pbuf  = (float*)(wsb + (30u << 20));                // 8 MB, alias cw (dead pre-attn)

  // conversions (element counts: x_q 2*1024*1024, x_kv 2*2048*1024 (!), ...)
  conv_f32_bf16<<<dim3(1024), 256, 0, stream>>>(x_q, xq_bf, 262144);
  conv_f32_bf16<<<dim3(512), 256, 0, stream>>>(W_q, wq_bf, 131072);
  conv_f32_bf16<<<dim3(2048), 256, 0, stream>>>(x_kv, xkv_bf, 524288);
  conv_f32_bf16<<<dim3(64), 256, 0, stream>>>(W_kvd, wkvd_bf, 16384);
  conv_f32_bf16<<<dim3(64), 256, 0, stream>>>(W_kvu + 131072, wv_bf, 16384);
  conv_f32_bf16<<<dim3(512), 256, 0, stream>>>(W_out, wout_bf, 131072);
  conv_wkt<<<dim3(512), 256, 0, stream>>>(W_kvu, wkt);

  // K2: c_kvb = bf16(x_kv @ W_kvd^T), split-K x4 (M=4096,N=128,K=1024)
  gemm_bf16_nt<false><<<dim3(2, 32, 4), 256, 0, stream>>>(
      xkv_bf, 1024, 256, wkvd_bf, 1024, 256, pbuf, nullptr,
      128, (long)4096 * 128, 256);
  reduce4b<<<dim3(512), 256, 0, stream>>>(c_kvb, pbuf, 131072);

  // K1: q_bf = bf16(x_q @ W_q^T)  (M=2048,N=1024,K=1024)
  gemm_bf16_nt<true><<<dim3(16, 16, 1), 256, 0, stream>>>(
      xq_bf, 1024, 0, wq_bf, 1024, 0, nullptr, q_bf, 1024, 0, 1024);

  // K3: qlat_bf[bq,h,:] = bf16(q[bq,h*64:] @ wkt[h]^T)  (M=2048,N=128,K=64, z=h)
  gemm_bf16_nt<true><<<dim3(2, 16, 16), 256, 0, stream>>>(
      q_bf, 1024, 64, wkt, 64, 8192, nullptr, qlat_bf, 2048, 128, 64);

  // K4: fused gather + latent scores + softmax + latent PV (bf16 MFMA)
  attn_mfma<<<dim3(2048), 256, 0, stream>>>(c_kvb, qlat_bf, idx, cw_bf);

  // K5: o_bf[bq,h*64+n] = bf16(cw[bq,h,:] @ W_v[h]^T)  (M=2048,N=64,K=128, z=h)
  gemm_bf16_nt<true><<<dim3(1, 16, 16), 256, 0, stream>>>(
      cw_bf, 2048, 128, wv_bf, 128, 8192, nullptr, o_bf, 1024, 64, 128);

  // K6: out = o @ W_out^T  (fp32 out)  (M=2048,N=1024,K=1024)
  gemm_bf16_nt<false><<<dim3(16, 16, 1), 256, 0, stream>>>(
      o_bf, 1024, 0, wout_bf, 1024, 0, out, nullptr, 1024, 0, 1024);
}

// Round 6
// 75.005 us; speedup vs baseline: 3.7445x; 1.2525x over previous
//
#include <hip/hip_runtime.h>

// DeepSeek-MLA sparse attention, absorbed formulation, full bf16-MFMA pipeline.
// B=2 NQ=1024 NKV=2048 K=64 D=1024 H=16 LAT=128 HD=64
// Round-6: (1) all conversions fused into one megaconv dispatch (13->8
// dispatches); (2) GEMM tile BM=64 (templated) so every grid >= 512 blocks
// = >=2 blocks/CU -- covers the 2-phase vmcnt drain with TLP (m114).
#define NKVc  2048
#define SCALE 0.125f

typedef unsigned short u16;
typedef __attribute__((ext_vector_type(8))) short short8b;     // 8 bf16 (MFMA frag)
typedef __attribute__((ext_vector_type(8))) unsigned short ushort8;
typedef __attribute__((ext_vector_type(4))) float f32x4;

__device__ __forceinline__ u16 f2bf(float f) {
  unsigned int u = __float_as_uint(f);
  return (u16)((u + 0x7FFFu + ((u >> 16) & 1u)) >> 16);   // RNE
}

// ---------------------------------------------------------------------------
// Mega-conversion: all fp32->bf16 prep in ONE dispatch. Unit = 8 elements.
// Segments (unit ranges):
//   [0,262144)        xq    2048x1024
//   [262144,393216)   wq    1024x1024
//   [393216,917504)   xkv   2x2048x1024
//   [917504,933888)   wkvd  128x1024
//   [933888,950272)   wv    W_kvu rows 1024..2048 (1024x128)
//   [950272,1081344)  wout  1024x1024
//   [1081344,1097728) wkt   transpose: wkt[((h*128)+l)*64+hd] = Wk[(h*64+hd)*128+l]
// grid = 1097728/256 = 4288 blocks.
// ---------------------------------------------------------------------------
__device__ __forceinline__ void conv8(const float* __restrict__ in,
                                      u16* __restrict__ out, int j) {
  float4 f0 = ((const float4*)in)[j * 2];
  float4 f1 = ((const float4*)in)[j * 2 + 1];
  ushort4 a, b;
  a.x = f2bf(f0.x); a.y = f2bf(f0.y); a.z = f2bf(f0.z); a.w = f2bf(f0.w);
  b.x = f2bf(f1.x); b.y = f2bf(f1.y); b.z = f2bf(f1.z); b.w = f2bf(f1.w);
  ((ushort4*)out)[j * 2] = a;
  ((ushort4*)out)[j * 2 + 1] = b;
}

__global__ __launch_bounds__(256)
void megaconv(const float* __restrict__ xq, const float* __restrict__ wq,
              const float* __restrict__ xkv, const float* __restrict__ wkvd,
              const float* __restrict__ wkvu, const float* __restrict__ wout,
              u16* __restrict__ xq_bf, u16* __restrict__ wq_bf,
              u16* __restrict__ xkv_bf, u16* __restrict__ wkvd_bf,
              u16* __restrict__ wv_bf, u16* __restrict__ wout_bf,
              u16* __restrict__ wkt) {
  int i = blockIdx.x * 256 + threadIdx.x;
  if (i < 262144) { conv8(xq, xq_bf, i); return; }
  if (i < 393216) { conv8(wq, wq_bf, i - 262144); return; }
  if (i < 917504) { conv8(xkv, xkv_bf, i - 393216); return; }
  if (i < 933888) { conv8(wkvd, wkvd_bf, i - 917504); return; }
  if (i < 950272) { conv8(wkvu + 131072, wv_bf, i - 933888); return; }
  if (i < 1081344) { conv8(wout, wout_bf, i - 950272); return; }
  {
    int o = (i - 1081344) * 8;          // 8 consecutive hd in one (h,l)
    int hd0 = o & 63;
    int l = (o >> 6) & 127;
    int h = o >> 13;
    const float* src = wkvu + (h * 64 + hd0) * 128 + l;
    ushort8 v;
#pragma unroll
    for (int j = 0; j < 8; ++j) v[j] = f2bf(src[j * 128]);
    *(ushort8*)&wkt[o] = v;
  }
}

// split-K reduce, bf16 out: dst[i] = bf16(sum_{p<4} src[p*n + i])
__global__ __launch_bounds__(256)
void reduce4b(u16* __restrict__ dst, const float* __restrict__ src, int n4) {
  int i = blockIdx.x * 256 + threadIdx.x;
  if (i >= n4) return;
  const float4* s = (const float4*)src;
  float4 a = s[i], b = s[i + n4], c = s[i + 2 * n4], d = s[i + 3 * n4];
  ushort4 v;
  v.x = f2bf(a.x + b.x + c.x + d.x); v.y = f2bf(a.y + b.y + c.y + d.y);
  v.z = f2bf(a.z + b.z + c.z + d.z); v.w = f2bf(a.w + b.w + c.w + d.w);
  ((ushort4*)dst)[i] = v;
}

// ---------------------------------------------------------------------------
// bf16 MFMA GEMM-NT, z-batched: C[m,n] = sum_k A[m,k]*B[n,k]
// BM template (64/128), BN=64, BK=32, 256 thr / 4 waves (2x2);
// wave tile (BM/2)x32, acc (BM/32)x2. OBF: write bf16 to Cb.
// Both-sides XOR swizzle + global_load_lds w=16 + 2-phase double buffer.
// ---------------------------------------------------------------------------
template<int BM, bool OBF>
__global__ __launch_bounds__(256)
void gemm_bf16_nt(const u16* __restrict__ A, int lda, long sAz,
                  const u16* __restrict__ B, int ldb, long sBz,
                  float* __restrict__ C, u16* __restrict__ Cb,
                  int ldc, long sCz, int K) {
  A += (size_t)blockIdx.z * sAz;
  B += (size_t)blockIdx.z * sBz;
  constexpr int ASLOT = BM * 4;                  // 16B slots in A tile
  constexpr int MF = BM / 32;                    // m-frags per wave
  __shared__ __align__(16) u16 As[2][ASLOT * 8];
  __shared__ __align__(16) u16 Bs[2][256 * 8];
  const int tid = threadIdx.x;
  const int w = tid >> 6, lane = tid & 63;
  const int bm = blockIdx.y * BM, bn = blockIdx.x * 64;
  const int wr = w >> 1, wc = w & 1;

  f32x4 acc[MF][2] = {};

  auto stage = [&](int buf, int k0) {
#pragma unroll
    for (int t = 0; t < BM / 64; ++t) {
      int s = w * (ASLOT / 4) + t * 64 + lane;
      int row = s >> 2;
      int kc = (s & 3) ^ ((row >> 1) & 3);
      const u16* g = A + (size_t)(bm + row) * lda + (k0 + kc * 8);
      __builtin_amdgcn_global_load_lds(
          (const __attribute__((address_space(1))) unsigned int*)g,
          (__attribute__((address_space(3))) unsigned int*)&As[buf][(w * (ASLOT / 4) + t * 64) * 8],
          16, 0, 0);
    }
    {
      int s = w * 64 + lane;
      int row = s >> 2;
      int kc = (s & 3) ^ ((row >> 1) & 3);
      const u16* g = B + (size_t)(bn + row) * ldb + (k0 + kc * 8);
      __builtin_amdgcn_global_load_lds(
          (const __attribute__((address_space(1))) unsigned int*)g,
          (__attribute__((address_space(3))) unsigned int*)&Bs[buf][(w * 64) * 8],
          16, 0, 0);
    }
  };

  auto compute = [&](int buf) {
    short8b a[MF], b[2];
#pragma unroll
    for (int m = 0; m < MF; ++m) {
      int row = wr * (BM / 2) + m * 16 + (lane & 15);
      int slot = row * 4 + ((lane >> 4) ^ ((row >> 1) & 3));
      a[m] = *(const short8b*)&As[buf][slot * 8];
    }
#pragma unroll
    for (int n = 0; n < 2; ++n) {
      int col = wc * 32 + n * 16 + (lane & 15);
      int slot = col * 4 + ((lane >> 4) ^ ((col >> 1) & 3));
      b[n] = *(const short8b*)&Bs[buf][slot * 8];
    }
#pragma unroll
    for (int m = 0; m < MF; ++m)
#pragma unroll
      for (int n = 0; n < 2; ++n)
        acc[m][n] = __builtin_amdgcn_mfma_f32_16x16x32_bf16(a[m], b[n], acc[m][n], 0, 0, 0);
  };

  stage(0, 0);
  asm volatile("s_waitcnt vmcnt(0)" ::: "memory");
  __syncthreads();
  const int nk = K >> 5;
  for (int t = 0; t < nk; ++t) {
    int cur = t & 1;
    if (t + 1 < nk) stage(cur ^ 1, (t + 1) << 5);
    compute(cur);
    asm volatile("s_waitcnt vmcnt(0)" ::: "memory");
    __syncthreads();
  }

#pragma unroll
  for (int m = 0; m < MF; ++m) {
    int row0 = bm + wr * (BM / 2) + m * 16 + (lane >> 4) * 4;
#pragma unroll
    for (int n = 0; n < 2; ++n) {
      int col = bn + wc * 32 + n * 16 + (lane & 15);
      if constexpr (OBF) {
        u16* Cz = Cb + (size_t)blockIdx.z * sCz;
#pragma unroll
        for (int r = 0; r < 4; ++r)
          Cz[(size_t)(row0 + r) * ldc + col] = f2bf(acc[m][n][r]);
      } else {
        float* Cz = C + (size_t)blockIdx.z * sCz;
#pragma unroll
        for (int r = 0; r < 4; ++r)
          Cz[(size_t)(row0 + r) * ldc + col] = acc[m][n][r];
      }
    }
  }
}

// ---------------------------------------------------------------------------
// Fused sparse attention in latent space, bf16 MFMA. One block per (b,q).
// scores = cs(64x128) x qls^T(16x128) -> softmax_k -> cw = P^T(16x64) x cs.
// ---------------------------------------------------------------------------
__global__ __launch_bounds__(256)
void attn_mfma(const u16* __restrict__ c_kvb,   // (B, 2048, 128) bf16
               const u16* __restrict__ q_latb,  // (BQ, 16, 128) bf16
               const int* __restrict__ indices, // (BQ, 64)
               u16* __restrict__ cw_bf) {       // (BQ, 16, 128) bf16
  __shared__ __align__(16) u16 qls[256 * 8];    // 4 KB swizzled 16x128
  __shared__ __align__(16) u16 csa[1024 * 8];   // 16 KB swizzled 64x128
  __shared__ __align__(16) u16 cst[128 * 72];   // 18 KB [lat][k]+pad
  __shared__ __align__(16) u16 pT[16 * 72];     // P^T [h][k]+pad
  __shared__ __align__(16) float redmax[64];
  __shared__ __align__(16) float redsum[64];
  __shared__ __align__(16) u16 outst[2048];     // 4 KB out staging

  const int tid = threadIdx.x;
  const int w = tid >> 6, lane = tid & 63;
  const int bq = blockIdx.x;
  const int b = bq >> 10;

  // load q_lat 16x128 bf16, chunk-XOR swizzle: slot = h*16 + (c^h)
  {
    int h = tid >> 4, c = tid & 15;
    ushort8 v = *(const ushort8*)(q_latb + (size_t)bq * 2048 + tid * 8);
    *(ushort8*)&qls[(h * 16 + (c ^ h)) * 8] = v;
  }
  // gather: wave w owns lat quarter [w*32, w*32+32), lane owns k-row `lane`
  {
    int kidx = indices[bq * 64 + lane];
    const u16* src = c_kvb + ((size_t)b * NKVc + kidx) * 128 + w * 32;
    ushort8 v[4];
#pragma unroll
    for (int t = 0; t < 4; ++t) v[t] = *(const ushort8*)(src + t * 8);
#pragma unroll
    for (int t = 0; t < 4; ++t) {
      int c = w * 4 + t;
      *(ushort8*)&csa[(lane * 16 + (c ^ (lane & 15))) * 8] = v[t];
    }
#pragma unroll
    for (int t = 0; t < 4; ++t)
#pragma unroll
      for (int j = 0; j < 8; ++j)
        cst[(w * 32 + t * 8 + j) * 72 + lane] = v[t][j];
  }
  __syncthreads();

  // scores: wave w -> S[k = w*16 + (lane>>4)*4 + r][h = lane&15]
  f32x4 sacc = {};
#pragma unroll
  for (int kc = 0; kc < 4; ++kc) {
    int ar = w * 16 + (lane & 15);
    int ac = kc * 4 + (lane >> 4);
    short8b av = *(const short8b*)&csa[(ar * 16 + (ac ^ (ar & 15))) * 8];
    int bh = lane & 15;
    short8b bv = *(const short8b*)&qls[(bh * 16 + (ac ^ bh)) * 8];
    sacc = __builtin_amdgcn_mfma_f32_16x16x32_bf16(av, bv, sacc, 0, 0, 0);
  }
  float s0 = sacc[0] * SCALE, s1 = sacc[1] * SCALE;
  float s2 = sacc[2] * SCALE, s3 = sacc[3] * SCALE;
  float mx = fmaxf(fmaxf(s0, s1), fmaxf(s2, s3));
  mx = fmaxf(mx, __shfl_xor(mx, 16));
  mx = fmaxf(mx, __shfl_xor(mx, 32));
  if (lane < 16) redmax[w * 16 + lane] = mx;
  __syncthreads();
  const int h = lane & 15;
  float m4 = fmaxf(fmaxf(redmax[h], redmax[16 + h]),
                   fmaxf(redmax[32 + h], redmax[48 + h]));
  float p0 = __expf(s0 - m4), p1 = __expf(s1 - m4);
  float p2 = __expf(s2 - m4), p3 = __expf(s3 - m4);
  float sm = p0 + p1 + p2 + p3;
  sm += __shfl_xor(sm, 16);
  sm += __shfl_xor(sm, 32);
  if (lane < 16) redsum[w * 16 + lane] = sm;
  __syncthreads();
  float tot = redsum[h] + redsum[16 + h] + redsum[32 + h] + redsum[48 + h];
  float inv = 1.0f / tot;
  {
    ushort4 pw;
    pw.x = f2bf(p0 * inv); pw.y = f2bf(p1 * inv);
    pw.z = f2bf(p2 * inv); pw.w = f2bf(p3 * inv);
    *(ushort4*)&pT[h * 72 + w * 16 + (lane >> 4) * 4] = pw;
  }
  __syncthreads();

  // PV: wave w computes C[h 0..15][n = w*32 .. w*32+32]
  f32x4 pacc0 = {}, pacc1 = {};
#pragma unroll
  for (int kc = 0; kc < 2; ++kc) {
    short8b pa = *(const short8b*)&pT[(lane & 15) * 72 + kc * 32 + (lane >> 4) * 8];
    int cch = kc * 4 + (lane >> 4);
    int n0 = w * 32 + (lane & 15);
    short8b b0 = *(const short8b*)&cst[n0 * 72 + cch * 8];
    short8b b1 = *(const short8b*)&cst[(n0 + 16) * 72 + cch * 8];
    pacc0 = __builtin_amdgcn_mfma_f32_16x16x32_bf16(pa, b0, pacc0, 0, 0, 0);
    pacc1 = __builtin_amdgcn_mfma_f32_16x16x32_bf16(pa, b1, pacc1, 0, 0, 0);
  }
#pragma unroll
  for (int r = 0; r < 4; ++r) {
    int hh = (lane >> 4) * 4 + r;
    outst[hh * 128 + w * 32 + (lane & 15)] = f2bf(pacc0[r]);
    outst[hh * 128 + w * 32 + 16 + (lane & 15)] = f2bf(pacc1[r]);
  }
  __syncthreads();
  *(ushort8*)(cw_bf + (size_t)bq * 2048 + tid * 8) = *(const ushort8*)&outst[tid * 8];
}

extern "C" void kernel_launch(void* const* d_in, const int* in_sizes, int n_in,
                              void* d_out, int out_size, void* d_ws, size_t ws_size,
                              hipStream_t stream) {
  const float* x_q    = (const float*)d_in[0];
  const float* x_kv   = (const float*)d_in[1];
  const int*   idx    = (const int*)  d_in[2];
  const float* W_q    = (const float*)d_in[3];
  const float* W_kvd  = (const float*)d_in[4];
  const float* W_kvu  = (const float*)d_in[5];
  const float* W_out  = (const float*)d_in[6];
  float* out = (float*)d_out;

  // byte-offset workspace carve; top = 42 MB (round-5-proven footprint)
  char* wsb = (char*)d_ws;
  u16* xq_bf   = (u16*)(wsb + 0);                            // 4 MB
  u16* wq_bf   = (u16*)(wsb + (4u << 20));                   // 2 MB
  u16* xkv_bf  = (u16*)(wsb + (6u << 20));                   // 8 MB
  u16* wkvd_bf = (u16*)(wsb + (14u << 20));                  // 256 KB
  u16* wkt     = (u16*)(wsb + (14u << 20) + (256u << 10));   // 256 KB
  u16* wv_bf   = (u16*)(wsb + (14u << 20) + (512u << 10));   // 256 KB
  u16* wout_bf = (u16*)(wsb + (14u << 20) + (768u << 10));   // 2 MB
  u16* q_bf    = (u16*)(wsb + (17u << 20));                  // 4 MB
  u16* c_kvb   = (u16*)(wsb + (21u << 20));                  // 1 MB
  u16* qlat_bf = (u16*)(wsb + (22u << 20));                  // 8 MB
  u16* cw_bf   = (u16*)(wsb + (30u << 20));                  // 8 MB
  u16* o_bf    = (u16*)(wsb + (38u << 20));                  // 4 MB
  float* pbuf  = (float*)(wsb + (30u << 20));                // 8 MB, alias cw (dead pre-attn)

  // C0: all conversions in one dispatch
  megaconv<<<dim3(4288), 256, 0, stream>>>(x_q, W_q, x_kv, W_kvd, W_kvu, W_out,
                                           xq_bf, wq_bf, xkv_bf, wkvd_bf,
                                           wv_bf, wout_bf, wkt);

  // K2: c_kvb = bf16(x_kv @ W_kvd^T), split-K x4 (M=4096,N=128,K=1024)
  gemm_bf16_nt<64, false><<<dim3(2, 64, 4), 256, 0, stream>>>(
      xkv_bf, 1024, 256, wkvd_bf, 1024, 256, pbuf, nullptr,
      128, (long)4096 * 128, 256);
  reduce4b<<<dim3(512), 256, 0, stream>>>(c_kvb, pbuf, 131072);

  // K1: q_bf = bf16(x_q @ W_q^T)  (M=2048,N=1024,K=1024) -> 512 blocks
  gemm_bf16_nt<64, true><<<dim3(16, 32, 1), 256, 0, stream>>>(
      xq_bf, 1024, 0, wq_bf, 1024, 0, nullptr, q_bf, 1024, 0, 1024);

  // K3: qlat_bf[bq,h,:] = bf16(q[bq,h*64:] @ wkt[h]^T)  (M=2048,N=128,K=64, z=h)
  gemm_bf16_nt<64, true><<<dim3(2, 32, 16), 256, 0, stream>>>(
      q_bf, 1024, 64, wkt, 64, 8192, nullptr, qlat_bf, 2048, 128, 64);

  // K4: fused gather + latent scores + softmax + latent PV (bf16 MFMA)
  attn_mfma<<<dim3(2048), 256, 0, stream>>>(c_kvb, qlat_bf, idx, cw_bf);

  // K5: o_bf[bq,h*64+n] = bf16(cw[bq,h,:] @ W_v[h]^T)  (M=2048,N=64,K=128, z=h)
  gemm_bf16_nt<64, true><<<dim3(1, 32, 16), 256, 0, stream>>>(
      cw_bf, 2048, 128, wv_bf, 128, 8192, nullptr, o_bf, 1024, 64, 128);

  // K6: out = o @ W_out^T  (fp32 out)  (M=2048,N=1024,K=1024) -> 512 blocks
  gemm_bf16_nt<64, false><<<dim3(16, 32, 1), 256, 0, stream>>>(
      o_bf, 1024, 0, wout_bf, 1024, 0, out, nullptr, 1024, 0, 1024);
}